// Round 6
// baseline (231.328 us; speedup 1.0000x reference)
//
#include <hip/hip_runtime.h>
#include <hip/hip_bf16.h>
#include <stdint.h>

// ---------------- problem constants ----------------
#define T_  4
#define B_  4
#define C_  512
#define N_  1024       // H*W
#define NH_ 8
#define HD_ 64
#define NP_ 16384      // T*B*N
#define EPS_ 1e-5f

typedef __bf16 bf16_t;
typedef __bf16 bf16x8 __attribute__((ext_vector_type(8)));
typedef float  f32x4  __attribute__((ext_vector_type(4)));
typedef unsigned short u16x4 __attribute__((ext_vector_type(4)));
typedef unsigned char  u8x4  __attribute__((ext_vector_type(4)));
typedef unsigned long long u64;
typedef unsigned int u32;

// ---------------- workspace layout (bytes) ----------------
#define XS_OFF   0ULL                      // bf16 XsT[16384][512] ; later osT
#define AHI_OFF  16777216ULL               // bf16 [1536][512]  stacked Wq/Wk/Wv hi
#define ALO_OFF  18350080ULL               // bf16 [1536][512]  lo
#define PHI_OFF  19922944ULL               // bf16 [512][512]   Wp hi
#define PLO_OFF  20447232ULL               // bf16 [512][512]   Wp lo
#define SC_OFF   20971520ULL               // f32 [1536] BN scale (stacked q,k,v)
#define SH_OFF   20977664ULL               // f32 [1536] BN shift
#define PSC_OFF  20983808ULL               // f32 [512]
#define PSH_OFF  20985856ULL               // f32 [512]  (includes bp folded)
#define QS_OFF   20987904ULL               // bf16 qsT[16384][512]  q spikes (transposed)
#define KB_OFF   37765120ULL               // u64 [16][8][64][16] k spike bits
#define VB_OFF   38813696ULL               // u64 [16][8][64][16]
#define M2H_OFF  39862272ULL               // bf16 M2T_hi[128][64][64]
#define M2L_OFF  40910848ULL               // bf16 M2T_lo[128][64][64]

// =====================================================================
// K0: weight split (hi/lo bf16) + BN constant folding
// =====================================================================
__global__ __launch_bounds__(256) void prep_kernel(
    const float* __restrict__ Wq, const float* __restrict__ Wk,
    const float* __restrict__ Wv, const float* __restrict__ Wp,
    const float* __restrict__ qg, const float* __restrict__ qb, const float* __restrict__ qm, const float* __restrict__ qv,
    const float* __restrict__ kg, const float* __restrict__ kb, const float* __restrict__ km, const float* __restrict__ kv,
    const float* __restrict__ vg, const float* __restrict__ vb, const float* __restrict__ vm, const float* __restrict__ vv,
    const float* __restrict__ bp,
    const float* __restrict__ pg, const float* __restrict__ pb, const float* __restrict__ pm, const float* __restrict__ pv,
    bf16_t* __restrict__ Ahi, bf16_t* __restrict__ Alo,
    bf16_t* __restrict__ Phi, bf16_t* __restrict__ Plo,
    float* __restrict__ scale, float* __restrict__ shift,
    float* __restrict__ pscale, float* __restrict__ pshift)
{
    const int i0 = blockIdx.x * 256 + threadIdx.x;
    const int stride = gridDim.x * 256;
    for (int idx = i0; idx < 1536 * 512; idx += stride) {
        int r = idx >> 9;
        int br = r >> 9;
        const float* W = (br == 0) ? Wq : (br == 1) ? Wk : Wv;
        float w = W[((r & 511) << 9) + (idx & 511)];
        bf16_t h = (bf16_t)w;
        Ahi[idx] = h;
        Alo[idx] = (bf16_t)(w - (float)h);
    }
    for (int idx = i0; idx < 512 * 512; idx += stride) {
        float w = Wp[idx];
        bf16_t h = (bf16_t)w;
        Phi[idx] = h;
        Plo[idx] = (bf16_t)(w - (float)h);
    }
    for (int idx = i0; idx < 1536; idx += stride) {
        int br = idx >> 9, d = idx & 511;
        const float* g  = (br == 0) ? qg : (br == 1) ? kg : vg;
        const float* bb = (br == 0) ? qb : (br == 1) ? kb : vb;
        const float* mm = (br == 0) ? qm : (br == 1) ? km : vm;
        const float* vr = (br == 0) ? qv : (br == 1) ? kv : vv;
        float sc = g[d] / sqrtf(vr[d] + EPS_);
        scale[idx] = sc;
        shift[idx] = bb[d] - mm[d] * sc;
    }
    for (int idx = i0; idx < 512; idx += stride) {
        float sc = pg[idx] / sqrtf(pv[idx] + EPS_);
        pscale[idx] = sc;
        pshift[idx] = (bp[idx] - pm[idx]) * sc + pb[idx];
    }
}

// =====================================================================
// K1: proj_lif on x -> spikes, transposed XsT[n'][c], coalesced via LDS
// =====================================================================
__global__ __launch_bounds__(256) void lif_x_kernel(const float* __restrict__ x,
                                                    bf16_t* __restrict__ xsT)
{
    __shared__ bf16_t St[64 * 72];
    const int tid = threadIdx.x;
    const int nl  = tid & 63;
    const int c4  = tid >> 6;
    const int n0 = blockIdx.x * 64;
    const int c0 = blockIdx.y * 64;
    const int b  = blockIdx.z;
    float v[16];
#pragma unroll
    for (int k = 0; k < 16; ++k) v[k] = 0.f;

    for (int t = 0; t < T_; ++t) {
        bf16x8 s0, s1;
#pragma unroll
        for (int k = 0; k < 16; ++k) {
            float xv = x[(size_t)((t * B_ + b) * C_ + (c0 + c4 * 16 + k)) * N_ + n0 + nl];
            float vn = v[k] + (xv - v[k]) * 0.5f;
            bool s = (vn >= 1.0f);
            v[k] = s ? 0.0f : vn;
            bf16_t sp = s ? (bf16_t)1.0f : (bf16_t)0.0f;
            if (k < 8) s0[k] = sp; else s1[k - 8] = sp;
        }
        __syncthreads();
        *(bf16x8*)&St[nl * 72 + c4 * 16]     = s0;
        *(bf16x8*)&St[nl * 72 + c4 * 16 + 8] = s1;
        __syncthreads();
#pragma unroll
        for (int it = 0; it < 2; ++it) {
            int id = it * 256 + tid;
            int row = id >> 3, sg = id & 7;
            *(bf16x8*)&xsT[((size_t)((t * B_ + b) << 10) + n0 + row) * C_ + c0 + sg * 8] =
                *(const bf16x8*)&St[row * 72 + sg * 8];
        }
    }
}

// =====================================================================
// K2: FUSED qkv GEMM + BN + LIF + spike emit  (t-inner acc, 2-phase dbuf).
//  BM=128 channels, 32 sites x 4t, BK=32, double-buffered (2 x 24KB).
//  Buffer: A[128 rows][8 chunks16B] (hi/lo interleaved, XOR row&7)
//          B[32 sites][16 chunks]  (t in low chunk bits, XOR row&15)
//  Loop: STAGE(next) ; ds_read+MFMA(cur) ; __syncthreads (drains vmcnt).
// =====================================================================
__global__ __launch_bounds__(256) void gemm_qkv_lif(
    const bf16_t* __restrict__ Ahi, const bf16_t* __restrict__ Alo,
    const bf16_t* __restrict__ xsT,
    const float* __restrict__ scale, const float* __restrict__ shift,
    bf16_t* __restrict__ qsT, u32* __restrict__ kbits, u32* __restrict__ vbits)
{
    __shared__ __align__(16) unsigned char smem[49152];   // 2 x (A 16K + B 8K)

    const int tid  = threadIdx.x;
    const int lane = tid & 63;
    const int wv   = tid >> 6;
    const int wr   = wv >> 1, wc = wv & 1;     // wave tile 64(c) x 16(sites)
    const int m0   = blockIdx.y * 128;
    const int branch = m0 >> 9;                // 0=q 1=k 2=v
    const int site0 = blockIdx.x * 32;
    const int b    = site0 >> 10;
    const int n0   = site0 & 1023;

    const int frow = lane & 15;
    const int g4   = lane >> 4;

    f32x4 acc[4][4];                           // [t][mi]
#pragma unroll
    for (int t = 0; t < 4; ++t)
#pragma unroll
        for (int mi = 0; mi < 4; ++mi) acc[t][mi] = f32x4{0.f, 0.f, 0.f, 0.f};

    // ---- staging helper (BK=32 tile into buffer `buf`) ----
    auto stage = [&](int buf, int kk) {
        unsigned char* Ab = smem + buf * 24576;
        unsigned char* Bb = Ab + 16384;
#pragma unroll
        for (int p = 0; p < 4; ++p) {          // A: 128 rows x 8 chunks
            int s = p * 256 + tid;
            int row = s >> 3, j = s & 7;
            int jp = j ^ (row & 7);
            const bf16_t* srcp = (jp & 4) ? Alo : Ahi;
            size_t goff = (size_t)(m0 + row) * 512 + kk + (jp & 3) * 8;
            __builtin_amdgcn_global_load_lds(
                (const __attribute__((address_space(1))) void*)(srcp + goff),
                (__attribute__((address_space(3))) void*)(Ab + (p * 256 + wv * 64) * 16), 16, 0, 0);
        }
#pragma unroll
        for (int p = 0; p < 2; ++p) {          // B: 32 sites x 16 chunks
            int s = p * 256 + tid;
            int row = s >> 4, j = s & 15;
            int jp = j ^ (row & 15);
            int tt = jp & 3, c = jp >> 2;
            size_t goff = ((size_t)((tt * B_ + b) << 10) + n0 + row) * 512 + kk + c * 8;
            __builtin_amdgcn_global_load_lds(
                (const __attribute__((address_space(1))) void*)(xsT + goff),
                (__attribute__((address_space(3))) void*)(Bb + (p * 256 + wv * 64) * 16), 16, 0, 0);
        }
    };

    stage(0, 0);
    __syncthreads();
    int cur = 0;
    for (int step = 0; step < 16; ++step) {
        if (step < 15) stage(cur ^ 1, (step + 1) * 32);

        unsigned char* Ab = smem + cur * 24576;
        unsigned char* Bb = Ab + 16384;
        bf16x8 ah[4], al[4];
#pragma unroll
        for (int mi = 0; mi < 4; ++mi) {
            int row = wr * 64 + mi * 16 + frow;
            int jh = g4 ^ (row & 7);
            int jl = (4 + g4) ^ (row & 7);
            ah[mi] = *(const bf16x8*)(Ab + row * 128 + jh * 16);
            al[mi] = *(const bf16x8*)(Ab + row * 128 + jl * 16);
        }
#pragma unroll
        for (int t = 0; t < 4; ++t) {
            int rowb = wc * 16 + frow;
            int jb = (g4 * 4 + t) ^ (rowb & 15);
            bf16x8 bb = *(const bf16x8*)(Bb + rowb * 256 + jb * 16);
#pragma unroll
            for (int mi = 0; mi < 4; ++mi) {
                acc[t][mi] = __builtin_amdgcn_mfma_f32_16x16x32_bf16(ah[mi], bb, acc[t][mi], 0, 0, 0);
                acc[t][mi] = __builtin_amdgcn_mfma_f32_16x16x32_bf16(al[mi], bb, acc[t][mi], 0, 0, 0);
            }
        }
        __syncthreads();      // drains vmcnt (stage) + lgkm; frees cur buffer
        cur ^= 1;
    }

    // ---------------- epilogue: BN + LIF chain + emit ----------------
    if (branch == 0) {
        bf16_t* Tt = (bf16_t*)smem;            // [32 sites][136] stride
        u16x4 qpk[4][4];                       // [t][mi]
#pragma unroll
        for (int mi = 0; mi < 4; ++mi)
#pragma unroll
            for (int r = 0; r < 4; ++r) {
                int gr = m0 + wr * 64 + mi * 16 + g4 * 4 + r;
                float sc = scale[gr], sh = shift[gr];
                float vv = 0.f;
#pragma unroll
                for (int t = 0; t < 4; ++t) {
                    float y = acc[t][mi][r] * sc + sh;
                    float vn = vv + (y - vv) * 0.5f;
                    bool s = (vn >= 1.0f);
                    vv = s ? 0.f : vn;
                    qpk[t][mi][r] = s ? 0x3F80 : 0;
                }
            }
#pragma unroll
        for (int t = 0; t < 4; ++t) {
            const int tb = t * B_ + b;
            __syncthreads();
#pragma unroll
            for (int mi = 0; mi < 4; ++mi) {
                int nl = wc * 16 + frow;
                int cl = wr * 64 + mi * 16 + g4 * 4;
                *(u16x4*)&Tt[nl * 136 + cl] = qpk[t][mi];
            }
            __syncthreads();
#pragma unroll
            for (int it = 0; it < 2; ++it) {
                int id = it * 256 + tid;
                int row = id >> 4, sg = id & 15;
                *(bf16x8*)&qsT[((size_t)(tb << 10) + n0 + row) * 512 + m0 + sg * 8] =
                    *(const bf16x8*)&Tt[row * 136 + sg * 8];
            }
        }
    } else {
        unsigned char* Sb = (unsigned char*)smem;   // [32 sites][132] stride
        u32* bdst = (branch == 1) ? kbits : vbits;
        u8x4 kpk[4][4];
#pragma unroll
        for (int mi = 0; mi < 4; ++mi)
#pragma unroll
            for (int r = 0; r < 4; ++r) {
                int gr = m0 + wr * 64 + mi * 16 + g4 * 4 + r;
                float sc = scale[gr], sh = shift[gr];
                float vv = 0.f;
#pragma unroll
                for (int t = 0; t < 4; ++t) {
                    float y = acc[t][mi][r] * sc + sh;
                    float vn = vv + (y - vv) * 0.5f;
                    bool s = (vn >= 1.0f);
                    vv = s ? 0.f : vn;
                    kpk[t][mi][r] = s ? 1 : 0;
                }
            }
#pragma unroll
        for (int t = 0; t < 4; ++t) {
            const int tb = t * B_ + b;
            __syncthreads();
#pragma unroll
            for (int mi = 0; mi < 4; ++mi) {
                int nl = wc * 16 + frow;
                int cl = wr * 64 + mi * 16 + g4 * 4;
                *(u8x4*)&Sb[nl * 132 + cl] = kpk[t][mi];
            }
            __syncthreads();
#pragma unroll
            for (int i = 0; i < 16; ++i) {
                int item = wv * 16 + i;
                int c = item * 2 + (lane >> 5);
                unsigned char vb_ = Sb[(lane & 31) * 132 + c];
                u64 mask = __ballot(vb_ != 0);
                if (lane == 0) {
                    int r0 = (m0 & 511) + item * 2;
                    int r1 = r0 + 1;
                    bdst[((size_t)(tb * NH_ + (r0 >> 6)) * 64 + (r0 & 63)) * 32 + (n0 >> 5)] = (u32)mask;
                    bdst[((size_t)(tb * NH_ + (r1 >> 6)) * 64 + (r1 & 63)) * 32 + (n0 >> 5)] = (u32)(mask >> 32);
                }
            }
        }
    }
}

// =====================================================================
// K6: proj GEMM, same 2-phase dbuf structure.  BM=128, BN=128, BK=32.
//  Buffer: A[128][8 chunks] hi/lo interleaved ; B[64 ldsrows][8 chunks]
//  (2 sites/ldsrow, parity in chunk bit2, XOR ldsrow&7). BN+bias fused.
// =====================================================================
__global__ __launch_bounds__(256) void gemm_proj(
    const bf16_t* __restrict__ Phi, const bf16_t* __restrict__ Plo,
    const bf16_t* __restrict__ Bm,
    const float* __restrict__ scale, const float* __restrict__ shift,
    float* __restrict__ out)
{
    __shared__ __align__(16) unsigned char smem[49152];   // 2 x (A 16K + B 8K)

    const int tid  = threadIdx.x;
    const int lane = tid & 63;
    const int wv   = tid >> 6;
    const int wr   = wv >> 1, wc = wv & 1;     // wave tile 64(c) x 64(sites)
    const int m0   = blockIdx.y * 128;
    const int n0   = blockIdx.x * 128;         // site tile (within one tb)

    const int frow = lane & 15;
    const int g4   = lane >> 4;

    f32x4 acc[4][4];                           // [mi][ni]
#pragma unroll
    for (int i = 0; i < 4; ++i)
#pragma unroll
        for (int j = 0; j < 4; ++j) acc[i][j] = f32x4{0.f, 0.f, 0.f, 0.f};

    auto stage = [&](int buf, int kk) {
        unsigned char* Ab = smem + buf * 24576;
        unsigned char* Bb = Ab + 16384;
#pragma unroll
        for (int p = 0; p < 4; ++p) {          // A: 128 rows x 8 chunks
            int s = p * 256 + tid;
            int row = s >> 3, j = s & 7;
            int jp = j ^ (row & 7);
            const bf16_t* srcp = (jp & 4) ? Plo : Phi;
            size_t goff = (size_t)(m0 + row) * 512 + kk + (jp & 3) * 8;
            __builtin_amdgcn_global_load_lds(
                (const __attribute__((address_space(1))) void*)(srcp + goff),
                (__attribute__((address_space(3))) void*)(Ab + (p * 256 + wv * 64) * 16), 16, 0, 0);
        }
#pragma unroll
        for (int p = 0; p < 2; ++p) {          // B: 64 ldsrows x 8 chunks
            int s = p * 256 + tid;
            int lr = s >> 3, j = s & 7;
            int jp = j ^ (lr & 7);
            int site = lr * 2 + (jp >> 2);
            size_t goff = (size_t)(n0 + site) * 512 + kk + (jp & 3) * 8;
            __builtin_amdgcn_global_load_lds(
                (const __attribute__((address_space(1))) void*)(Bm + goff),
                (__attribute__((address_space(3))) void*)(Bb + (p * 256 + wv * 64) * 16), 16, 0, 0);
        }
    };

    stage(0, 0);
    __syncthreads();
    int cur = 0;
    for (int step = 0; step < 16; ++step) {
        if (step < 15) stage(cur ^ 1, (step + 1) * 32);

        unsigned char* Ab = smem + cur * 24576;
        unsigned char* Bb = Ab + 16384;
        bf16x8 ah[4], al[4], bb[4];
#pragma unroll
        for (int mi = 0; mi < 4; ++mi) {
            int row = wr * 64 + mi * 16 + frow;
            int jh = g4 ^ (row & 7);
            int jl = (4 + g4) ^ (row & 7);
            ah[mi] = *(const bf16x8*)(Ab + row * 128 + jh * 16);
            al[mi] = *(const bf16x8*)(Ab + row * 128 + jl * 16);
        }
#pragma unroll
        for (int ni = 0; ni < 4; ++ni) {
            int site = wc * 64 + ni * 16 + frow;
            int lr = site >> 1;
            int jb = ((site & 1) * 4 + g4) ^ (lr & 7);
            bb[ni] = *(const bf16x8*)(Bb + lr * 128 + jb * 16);
        }
#pragma unroll
        for (int mi = 0; mi < 4; ++mi)
#pragma unroll
            for (int ni = 0; ni < 4; ++ni) {
                acc[mi][ni] = __builtin_amdgcn_mfma_f32_16x16x32_bf16(ah[mi], bb[ni], acc[mi][ni], 0, 0, 0);
                acc[mi][ni] = __builtin_amdgcn_mfma_f32_16x16x32_bf16(al[mi], bb[ni], acc[mi][ni], 0, 0, 0);
            }
        __syncthreads();
        cur ^= 1;
    }

#pragma unroll
    for (int mi = 0; mi < 4; ++mi)
#pragma unroll
        for (int ni = 0; ni < 4; ++ni)
#pragma unroll
            for (int r = 0; r < 4; ++r) {
                int gr = m0 + wr * 64 + mi * 16 + g4 * 4 + r;
                int gc = n0 + wc * 64 + ni * 16 + frow;
                float vout = acc[mi][ni][r] * scale[gr] + shift[gr];
                int tb = gc >> 10, nn = gc & 1023;
                out[((size_t)(tb * C_ + gr)) * N_ + nn] = vout;
            }
}

// =====================================================================
// K4: M2T = (K^T V)^T * 0.125, exact hi/lo bf16 split.  One block per (tb,h).
// =====================================================================
__global__ __launch_bounds__(256) void m2t_kernel(const u64* __restrict__ kbit,
                                                  const u64* __restrict__ vbit,
                                                  bf16_t* __restrict__ m2h,
                                                  bf16_t* __restrict__ m2l)
{
    __shared__ u64 Kb[64][17];
    __shared__ u64 Vb[64][17];
    __shared__ float M2f[64][64];
    const int tid = threadIdx.x;
    const int h  = blockIdx.x;
    const int tb = blockIdx.y;

    const u64* kbase = kbit + (size_t)(tb * NH_ + h) * 1024;
    const u64* vbase = vbit + (size_t)(tb * NH_ + h) * 1024;
    for (int i = tid; i < 1024; i += 256) {
        Kb[i >> 4][i & 15] = kbase[i];
        Vb[i >> 4][i & 15] = vbase[i];
    }
    __syncthreads();

    const int d1 = tid >> 2, l2 = tid & 3;
    int cnt[16];
#pragma unroll
    for (int jj = 0; jj < 16; ++jj) cnt[jj] = 0;
    for (int w = 0; w < 16; ++w) {
        u64 kw = Kb[d1][w];
#pragma unroll
        for (int jj = 0; jj < 16; ++jj)
            cnt[jj] += __popcll(kw & Vb[l2 + 4 * jj][w]);
    }
#pragma unroll
    for (int jj = 0; jj < 16; ++jj)
        M2f[d1][l2 + 4 * jj] = (float)cnt[jj] * 0.125f;
    __syncthreads();

    const int d2 = tid >> 2, d1b = (tid & 3) * 16;
    bf16x8 h0, h1, l0, l1;
#pragma unroll
    for (int j = 0; j < 16; ++j) {
        float m = M2f[d1b + j][d2];
        bf16_t hi = (bf16_t)m;
        bf16_t lo = (bf16_t)(m - (float)hi);
        if (j < 8) { h0[j] = hi; l0[j] = lo; } else { h1[j - 8] = hi; l1[j - 8] = lo; }
    }
    size_t base = (size_t)(tb * NH_ + h) * 4096 + tid * 16;
    *(bf16x8*)&m2h[base]     = h0;
    *(bf16x8*)&m2h[base + 8] = h1;
    *(bf16x8*)&m2l[base]     = l0;
    *(bf16x8*)&m2l[base + 8] = l1;
}

// =====================================================================
// K5: O^T = M2T @ Q^T via MFMA (exact), fused attn-LIF, spikes -> osT.
// =====================================================================
__global__ __launch_bounds__(256) void o_kernel(const bf16_t* __restrict__ qsT,
                                                const bf16_t* __restrict__ m2h,
                                                const bf16_t* __restrict__ m2l,
                                                bf16_t* __restrict__ osT)
{
    __shared__ bf16_t Ah[64][72];
    __shared__ bf16_t Al[64][72];
    __shared__ bf16_t Bq[128][72];

    const int tid  = threadIdx.x;
    const int lane = tid & 63;
    const int wv   = tid >> 6;
    const int nt = blockIdx.x, h = blockIdx.y, b = blockIdx.z;
    const int n0 = nt * 128;
    const int frow = lane & 15;
    const int g    = lane >> 4;

    float vst[4][2][4];
#pragma unroll
    for (int mi = 0; mi < 4; ++mi)
#pragma unroll
        for (int ni = 0; ni < 2; ++ni)
#pragma unroll
            for (int r = 0; r < 4; ++r) vst[mi][ni][r] = 0.f;

    for (int t = 0; t < T_; ++t) {
        const int tb = t * B_ + b;
        __syncthreads();
        {
            int row = tid >> 2, col = (tid & 3) * 16;
            size_t gbase = (size_t)(tb * NH_ + h) * 4096 + row * 64 + col;
            *(bf16x8*)&Ah[row][col]     = *(const bf16x8*)&m2h[gbase];
            *(bf16x8*)&Ah[row][col + 8] = *(const bf16x8*)&m2h[gbase + 8];
            *(bf16x8*)&Al[row][col]     = *(const bf16x8*)&m2l[gbase];
            *(bf16x8*)&Al[row][col + 8] = *(const bf16x8*)&m2l[gbase + 8];
        }
#pragma unroll
        for (int w = 0; w < 4; ++w) {
            int id = w * 256 + tid;
            int row = id >> 3, cg = (id & 7) * 8;
            *(bf16x8*)&Bq[row][cg] =
                *(const bf16x8*)&qsT[(size_t)((tb << 10) + n0 + row) * C_ + h * 64 + cg];
        }
        __syncthreads();

        bf16x8 afh[4][2], afl[4][2], bfq[2][2];
#pragma unroll
        for (int mi = 0; mi < 4; ++mi)
#pragma unroll
            for (int ks = 0; ks < 2; ++ks) {
                afh[mi][ks] = *(const bf16x8*)&Ah[mi * 16 + frow][ks * 32 + g * 8];
                afl[mi][ks] = *(const bf16x8*)&Al[mi * 16 + frow][ks * 32 + g * 8];
            }
#pragma unroll
        for (int ni = 0; ni < 2; ++ni)
#pragma unroll
            for (int ks = 0; ks < 2; ++ks)
                bfq[ni][ks] = *(const bf16x8*)&Bq[wv * 32 + ni * 16 + frow][ks * 32 + g * 8];

        f32x4 acc[4][2];
#pragma unroll
        for (int mi = 0; mi < 4; ++mi)
#pragma unroll
            for (int ni = 0; ni < 2; ++ni) acc[mi][ni] = f32x4{0.f, 0.f, 0.f, 0.f};

#pragma unroll
        for (int ks = 0; ks < 2; ++ks)
#pragma unroll
            for (int mi = 0; mi < 4; ++mi)
#pragma unroll
                for (int ni = 0; ni < 2; ++ni) {
                    acc[mi][ni] = __builtin_amdgcn_mfma_f32_16x16x32_bf16(afh[mi][ks], bfq[ni][ks], acc[mi][ni], 0, 0, 0);
                    acc[mi][ni] = __builtin_amdgcn_mfma_f32_16x16x32_bf16(afl[mi][ks], bfq[ni][ks], acc[mi][ni], 0, 0, 0);
                }

#pragma unroll
        for (int mi = 0; mi < 4; ++mi)
#pragma unroll
            for (int ni = 0; ni < 2; ++ni) {
                ushort4 pk;
                unsigned short* pp = &pk.x;
#pragma unroll
                for (int r = 0; r < 4; ++r) {
                    float o = acc[mi][ni][r];
                    float vn = vst[mi][ni][r] + (o - vst[mi][ni][r]) * 0.5f;
                    bool s = (vn >= 0.5f);
                    vst[mi][ni][r] = s ? 0.f : vn;
                    pp[r] = s ? 0x3F80 : 0;
                }
                size_t off = (size_t)((tb << 10) + n0 + wv * 32 + ni * 16 + frow) * C_
                           + h * 64 + mi * 16 + g * 4;
                *(ushort4*)&osT[off] = pk;
            }
    }
}

// =====================================================================
extern "C" void kernel_launch(void* const* d_in, const int* in_sizes, int n_in,
                              void* d_out, int out_size, void* d_ws, size_t ws_size,
                              hipStream_t stream)
{
    const float* x   = (const float*)d_in[0];
    const float* Wq  = (const float*)d_in[1];
    const float* qg  = (const float*)d_in[2];
    const float* qb  = (const float*)d_in[3];
    const float* qm  = (const float*)d_in[4];
    const float* qv  = (const float*)d_in[5];
    const float* Wk  = (const float*)d_in[6];
    const float* kg  = (const float*)d_in[7];
    const float* kb  = (const float*)d_in[8];
    const float* km  = (const float*)d_in[9];
    const float* kv  = (const float*)d_in[10];
    const float* Wv  = (const float*)d_in[11];
    const float* vg  = (const float*)d_in[12];
    const float* vb  = (const float*)d_in[13];
    const float* vm  = (const float*)d_in[14];
    const float* vv  = (const float*)d_in[15];
    const float* Wp  = (const float*)d_in[16];
    const float* bp  = (const float*)d_in[17];
    const float* pg  = (const float*)d_in[18];
    const float* pb  = (const float*)d_in[19];
    const float* pm  = (const float*)d_in[20];
    const float* pv  = (const float*)d_in[21];

    char* ws = (char*)d_ws;
    bf16_t* xsT    = (bf16_t*)(ws + XS_OFF);
    bf16_t* Ahi    = (bf16_t*)(ws + AHI_OFF);
    bf16_t* Alo    = (bf16_t*)(ws + ALO_OFF);
    bf16_t* Phi    = (bf16_t*)(ws + PHI_OFF);
    bf16_t* Plo    = (bf16_t*)(ws + PLO_OFF);
    float*  scv    = (float*)(ws + SC_OFF);
    float*  shv    = (float*)(ws + SH_OFF);
    float*  psc    = (float*)(ws + PSC_OFF);
    float*  psh    = (float*)(ws + PSH_OFF);
    bf16_t* qsT    = (bf16_t*)(ws + QS_OFF);
    u32*    kbits32= (u32*)(ws + KB_OFF);
    u32*    vbits32= (u32*)(ws + VB_OFF);
    u64*    kbits  = (u64*)(ws + KB_OFF);
    u64*    vbits  = (u64*)(ws + VB_OFF);
    bf16_t* m2h    = (bf16_t*)(ws + M2H_OFF);
    bf16_t* m2l    = (bf16_t*)(ws + M2L_OFF);
    bf16_t* osT    = (bf16_t*)(ws + XS_OFF);   // ALIAS: xsT dead after gemm_qkv_lif
    float*  out    = (float*)d_out;

    prep_kernel<<<dim3(3072), dim3(256), 0, stream>>>(
        Wq, Wk, Wv, Wp, qg, qb, qm, qv, kg, kb, km, kv, vg, vb, vm, vv,
        bp, pg, pb, pm, pv, Ahi, Alo, Phi, Plo, scv, shv, psc, psh);

    lif_x_kernel<<<dim3(16, 8, 4), dim3(256), 0, stream>>>(x, xsT);

    gemm_qkv_lif<<<dim3(128, 12), dim3(256), 0, stream>>>(
        Ahi, Alo, xsT, scv, shv, qsT, kbits32, vbits32);

    m2t_kernel<<<dim3(8, 16), dim3(256), 0, stream>>>(kbits, vbits, m2h, m2l);

    o_kernel<<<dim3(8, 8, 4), dim3(256), 0, stream>>>(qsT, m2h, m2l, osT);

    gemm_proj<<<dim3(128, 4), dim3(256), 0, stream>>>(Phi, Plo, osT, psc, psh, out);

    (void)in_sizes; (void)n_in; (void)out_size; (void)ws_size;
}

// Round 7
// 216.626 us; speedup vs baseline: 1.0679x; 1.0679x over previous
//
#include <hip/hip_runtime.h>
#include <hip/hip_bf16.h>
#include <stdint.h>

// ---------------- problem constants ----------------
#define T_  4
#define B_  4
#define C_  512
#define N_  1024       // H*W
#define NH_ 8
#define HD_ 64
#define NP_ 16384      // T*B*N
#define EPS_ 1e-5f

typedef __bf16 bf16_t;
typedef __bf16 bf16x8 __attribute__((ext_vector_type(8)));
typedef float  f32x4  __attribute__((ext_vector_type(4)));
typedef unsigned short u16x4 __attribute__((ext_vector_type(4)));
typedef unsigned char  u8x4  __attribute__((ext_vector_type(4)));
typedef unsigned long long u64;
typedef unsigned int u32;

// ---------------- workspace layout (bytes) ----------------
#define XS_OFF   0ULL                      // bf16 XsT[16384][512] ; later osT
#define AHI_OFF  16777216ULL               // bf16 [1536][512]  stacked Wq/Wk/Wv hi
#define ALO_OFF  18350080ULL               // bf16 [1536][512]  lo
#define PHI_OFF  19922944ULL               // bf16 [512][512]   Wp hi
#define PLO_OFF  20447232ULL               // bf16 [512][512]   Wp lo
#define SC_OFF   20971520ULL               // f32 [1536] BN scale (stacked q,k,v)
#define SH_OFF   20977664ULL               // f32 [1536] BN shift
#define PSC_OFF  20983808ULL               // f32 [512]
#define PSH_OFF  20985856ULL               // f32 [512]  (includes bp folded)
#define QS_OFF   20987904ULL               // bf16 qsT[16384][512]  q spikes (transposed)
#define KB_OFF   37765120ULL               // u64 [16][8][64][16] k spike bits
#define VB_OFF   38813696ULL               // u64 [16][8][64][16]
#define M2H_OFF  39862272ULL               // bf16 M2T_hi[128][64][64]
#define M2L_OFF  40910848ULL               // bf16 M2T_lo[128][64][64]

// =====================================================================
// K0: weight split (hi/lo bf16) + BN constant folding
// =====================================================================
__global__ __launch_bounds__(256) void prep_kernel(
    const float* __restrict__ Wq, const float* __restrict__ Wk,
    const float* __restrict__ Wv, const float* __restrict__ Wp,
    const float* __restrict__ qg, const float* __restrict__ qb, const float* __restrict__ qm, const float* __restrict__ qv,
    const float* __restrict__ kg, const float* __restrict__ kb, const float* __restrict__ km, const float* __restrict__ kv,
    const float* __restrict__ vg, const float* __restrict__ vb, const float* __restrict__ vm, const float* __restrict__ vv,
    const float* __restrict__ bp,
    const float* __restrict__ pg, const float* __restrict__ pb, const float* __restrict__ pm, const float* __restrict__ pv,
    bf16_t* __restrict__ Ahi, bf16_t* __restrict__ Alo,
    bf16_t* __restrict__ Phi, bf16_t* __restrict__ Plo,
    float* __restrict__ scale, float* __restrict__ shift,
    float* __restrict__ pscale, float* __restrict__ pshift)
{
    const int i0 = blockIdx.x * 256 + threadIdx.x;
    const int stride = gridDim.x * 256;
    for (int idx = i0; idx < 1536 * 512; idx += stride) {
        int r = idx >> 9;
        int br = r >> 9;
        const float* W = (br == 0) ? Wq : (br == 1) ? Wk : Wv;
        float w = W[((r & 511) << 9) + (idx & 511)];
        bf16_t h = (bf16_t)w;
        Ahi[idx] = h;
        Alo[idx] = (bf16_t)(w - (float)h);
    }
    for (int idx = i0; idx < 512 * 512; idx += stride) {
        float w = Wp[idx];
        bf16_t h = (bf16_t)w;
        Phi[idx] = h;
        Plo[idx] = (bf16_t)(w - (float)h);
    }
    for (int idx = i0; idx < 1536; idx += stride) {
        int br = idx >> 9, d = idx & 511;
        const float* g  = (br == 0) ? qg : (br == 1) ? kg : vg;
        const float* bb = (br == 0) ? qb : (br == 1) ? kb : vb;
        const float* mm = (br == 0) ? qm : (br == 1) ? km : vm;
        const float* vr = (br == 0) ? qv : (br == 1) ? kv : vv;
        float sc = g[d] / sqrtf(vr[d] + EPS_);
        scale[idx] = sc;
        shift[idx] = bb[d] - mm[d] * sc;
    }
    for (int idx = i0; idx < 512; idx += stride) {
        float sc = pg[idx] / sqrtf(pv[idx] + EPS_);
        pscale[idx] = sc;
        pshift[idx] = (bp[idx] - pm[idx]) * sc + pb[idx];
    }
}

// =====================================================================
// K1: proj_lif on x -> spikes, transposed XsT[n'][c], coalesced via LDS
// =====================================================================
__global__ __launch_bounds__(256) void lif_x_kernel(const float* __restrict__ x,
                                                    bf16_t* __restrict__ xsT)
{
    __shared__ bf16_t St[64 * 72];
    const int tid = threadIdx.x;
    const int nl  = tid & 63;
    const int c4  = tid >> 6;
    const int n0 = blockIdx.x * 64;
    const int c0 = blockIdx.y * 64;
    const int b  = blockIdx.z;
    float v[16];
#pragma unroll
    for (int k = 0; k < 16; ++k) v[k] = 0.f;

    for (int t = 0; t < T_; ++t) {
        bf16x8 s0, s1;
#pragma unroll
        for (int k = 0; k < 16; ++k) {
            float xv = x[(size_t)((t * B_ + b) * C_ + (c0 + c4 * 16 + k)) * N_ + n0 + nl];
            float vn = v[k] + (xv - v[k]) * 0.5f;
            bool s = (vn >= 1.0f);
            v[k] = s ? 0.0f : vn;
            bf16_t sp = s ? (bf16_t)1.0f : (bf16_t)0.0f;
            if (k < 8) s0[k] = sp; else s1[k - 8] = sp;
        }
        __syncthreads();
        *(bf16x8*)&St[nl * 72 + c4 * 16]     = s0;
        *(bf16x8*)&St[nl * 72 + c4 * 16 + 8] = s1;
        __syncthreads();
#pragma unroll
        for (int it = 0; it < 2; ++it) {
            int id = it * 256 + tid;
            int row = id >> 3, sg = id & 7;
            *(bf16x8*)&xsT[((size_t)((t * B_ + b) << 10) + n0 + row) * C_ + c0 + sg * 8] =
                *(const bf16x8*)&St[row * 72 + sg * 8];
        }
    }
}

// =====================================================================
// K2: FUSED qkv GEMM + BN + LIF + spike emit  (t-inner accumulators).
//  ROUND-5 PROVEN VERSION (62.2 us): BM=128, BN=32 sites, BK=64,
//  single-buffer, 8 barrier-steps, 64 MFMA/step, XOR j^(row&7) swizzle.
// =====================================================================
__global__ __launch_bounds__(256) void gemm_qkv_lif(
    const bf16_t* __restrict__ Ahi, const bf16_t* __restrict__ Alo,
    const bf16_t* __restrict__ xsT,
    const float* __restrict__ scale, const float* __restrict__ shift,
    bf16_t* __restrict__ qsT, u32* __restrict__ kbits, u32* __restrict__ vbits)
{
    __shared__ __align__(16) unsigned char smem[49152];  // AH 16K | AL 16K | B 16K

    const int tid  = threadIdx.x;
    const int lane = tid & 63;
    const int wv   = tid >> 6;
    const int wr   = wv >> 1, wc = wv & 1;     // wave tile 64(c) x 16(sites)
    const int m0   = blockIdx.y * 128;         // stacked channel base
    const int branch = m0 >> 9;                // 0=q 1=k 2=v
    const int site0 = blockIdx.x * 32;
    const int b    = site0 >> 10;
    const int n0   = site0 & 1023;

    const int frow = lane & 15;
    const int g4   = lane >> 4;

    f32x4 acc[4][4];                           // [t][mi]
#pragma unroll
    for (int t = 0; t < 4; ++t)
#pragma unroll
        for (int mi = 0; mi < 4; ++mi) acc[t][mi] = f32x4{0.f, 0.f, 0.f, 0.f};

    for (int kk = 0; kk < 512; kk += 64) {
        __syncthreads();                       // prev step's readers done
        // ---- stage A hi/lo: 128 rows x 8 chunks(16B), swizzled source ----
#pragma unroll
        for (int p = 0; p < 4; ++p) {
            int s = p * 256 + tid;
            int row = s >> 3, j = s & 7;
            int kc = (j ^ (row & 7)) << 3;     // pre-swizzled source chunk
            size_t goff = (size_t)(m0 + row) * 512 + kk + kc;
            unsigned ldsb = (unsigned)(p * 256 + wv * 64) * 16;
            __builtin_amdgcn_global_load_lds((const __attribute__((address_space(1))) void*)(Ahi + goff),
                                             (__attribute__((address_space(3))) void*)(smem + ldsb), 16, 0, 0);
            __builtin_amdgcn_global_load_lds((const __attribute__((address_space(1))) void*)(Alo + goff),
                                             (__attribute__((address_space(3))) void*)(smem + 16384 + ldsb), 16, 0, 0);
        }
        // ---- stage B: 4t x 32 rows x 8 chunks ----
#pragma unroll
        for (int p = 0; p < 4; ++p) {
            int s = p * 256 + tid;
            int t = s >> 8, row = (s >> 3) & 31, j = s & 7;
            int kc = (j ^ (row & 7)) << 3;
            size_t goff = ((size_t)((t * B_ + b) << 10) + n0 + row) * 512 + kk + kc;
            unsigned ldsb = 32768u + (unsigned)(p * 256 + wv * 64) * 16;
            __builtin_amdgcn_global_load_lds((const __attribute__((address_space(1))) void*)(xsT + goff),
                                             (__attribute__((address_space(3))) void*)(smem + ldsb), 16, 0, 0);
        }
        __syncthreads();

        // ---- compute: 2 K-halves x 4 t x 4 mi x (hi+lo) ----
#pragma unroll
        for (int ks = 0; ks < 2; ++ks) {
            bf16x8 ah[4], al[4];
#pragma unroll
            for (int mi = 0; mi < 4; ++mi) {
                int row = wr * 64 + mi * 16 + frow;
                int jj = (ks * 4 + g4) ^ (row & 7);
                ah[mi] = *(const bf16x8*)(smem + row * 128 + jj * 16);
                al[mi] = *(const bf16x8*)(smem + 16384 + row * 128 + jj * 16);
            }
#pragma unroll
            for (int t = 0; t < 4; ++t) {
                int rowb = wc * 16 + frow;
                int jj = (ks * 4 + g4) ^ (rowb & 7);
                bf16x8 bb = *(const bf16x8*)(smem + 32768 + t * 4096 + rowb * 128 + jj * 16);
#pragma unroll
                for (int mi = 0; mi < 4; ++mi) {
                    acc[t][mi] = __builtin_amdgcn_mfma_f32_16x16x32_bf16(ah[mi], bb, acc[t][mi], 0, 0, 0);
                    acc[t][mi] = __builtin_amdgcn_mfma_f32_16x16x32_bf16(al[mi], bb, acc[t][mi], 0, 0, 0);
                }
            }
        }
    }

    // ---------------- epilogue: BN + LIF chain + emit ----------------
    if (branch == 0) {
        bf16_t* Tt = (bf16_t*)smem;            // [32 sites][136] stride
        u16x4 qpk[4][4];                       // [t][mi]
#pragma unroll
        for (int mi = 0; mi < 4; ++mi)
#pragma unroll
            for (int r = 0; r < 4; ++r) {
                int gr = m0 + wr * 64 + mi * 16 + g4 * 4 + r;
                float sc = scale[gr], sh = shift[gr];
                float vv = 0.f;
#pragma unroll
                for (int t = 0; t < 4; ++t) {
                    float y = acc[t][mi][r] * sc + sh;
                    float vn = vv + (y - vv) * 0.5f;
                    bool s = (vn >= 1.0f);
                    vv = s ? 0.f : vn;
                    qpk[t][mi][r] = s ? 0x3F80 : 0;
                }
            }
#pragma unroll
        for (int t = 0; t < 4; ++t) {
            const int tb = t * B_ + b;
            __syncthreads();
#pragma unroll
            for (int mi = 0; mi < 4; ++mi) {
                int nl = wc * 16 + frow;
                int cl = wr * 64 + mi * 16 + g4 * 4;
                *(u16x4*)&Tt[nl * 136 + cl] = qpk[t][mi];
            }
            __syncthreads();
#pragma unroll
            for (int it = 0; it < 2; ++it) {
                int id = it * 256 + tid;
                int row = id >> 4, sg = id & 15;
                *(bf16x8*)&qsT[((size_t)(tb << 10) + n0 + row) * 512 + m0 + sg * 8] =
                    *(const bf16x8*)&Tt[row * 136 + sg * 8];
            }
        }
    } else {
        unsigned char* Sb = (unsigned char*)smem;   // [32 sites][132] stride
        u32* bdst = (branch == 1) ? kbits : vbits;
        u8x4 kpk[4][4];
#pragma unroll
        for (int mi = 0; mi < 4; ++mi)
#pragma unroll
            for (int r = 0; r < 4; ++r) {
                int gr = m0 + wr * 64 + mi * 16 + g4 * 4 + r;
                float sc = scale[gr], sh = shift[gr];
                float vv = 0.f;
#pragma unroll
                for (int t = 0; t < 4; ++t) {
                    float y = acc[t][mi][r] * sc + sh;
                    float vn = vv + (y - vv) * 0.5f;
                    bool s = (vn >= 1.0f);
                    vv = s ? 0.f : vn;
                    kpk[t][mi][r] = s ? 1 : 0;
                }
            }
#pragma unroll
        for (int t = 0; t < 4; ++t) {
            const int tb = t * B_ + b;
            __syncthreads();
#pragma unroll
            for (int mi = 0; mi < 4; ++mi) {
                int nl = wc * 16 + frow;
                int cl = wr * 64 + mi * 16 + g4 * 4;
                *(u8x4*)&Sb[nl * 132 + cl] = kpk[t][mi];
            }
            __syncthreads();
#pragma unroll
            for (int i = 0; i < 16; ++i) {
                int item = wv * 16 + i;
                int c = item * 2 + (lane >> 5);
                unsigned char vb_ = Sb[(lane & 31) * 132 + c];
                u64 mask = __ballot(vb_ != 0);
                if (lane == 0) {
                    int r0 = (m0 & 511) + item * 2;
                    int r1 = r0 + 1;
                    bdst[((size_t)(tb * NH_ + (r0 >> 6)) * 64 + (r0 & 63)) * 32 + (n0 >> 5)] = (u32)mask;
                    bdst[((size_t)(tb * NH_ + (r1 >> 6)) * 64 + (r1 & 63)) * 32 + (n0 >> 5)] = (u32)(mask >> 32);
                }
            }
        }
    }
}

// =====================================================================
// K6: proj GEMM — geometry clone of the proven round-5 qkv structure.
//  BM=128, BN=128 sites, BK=64, single-buffer 48K LDS, 8 barrier-steps,
//  64 MFMA/step, XOR j^(row&7) swizzle on stage-source and read.
//  BN+bias fused; out = d_out [T*B][C][N].
// =====================================================================
__global__ __launch_bounds__(256) void gemm_proj(
    const bf16_t* __restrict__ Phi, const bf16_t* __restrict__ Plo,
    const bf16_t* __restrict__ Bm,
    const float* __restrict__ scale, const float* __restrict__ shift,
    float* __restrict__ out)
{
    __shared__ __align__(16) unsigned char smem[49152];  // AH 16K | AL 16K | B 16K

    const int tid  = threadIdx.x;
    const int lane = tid & 63;
    const int wv   = tid >> 6;
    const int wr   = wv >> 1, wc = wv & 1;     // wave tile 64(c) x 64(sites)
    const int m0   = blockIdx.y * 128;
    const int n0   = blockIdx.x * 128;         // global site column base

    const int frow = lane & 15;
    const int g4   = lane >> 4;

    f32x4 acc[4][4];                           // [mi][ni]
#pragma unroll
    for (int i = 0; i < 4; ++i)
#pragma unroll
        for (int j = 0; j < 4; ++j) acc[i][j] = f32x4{0.f, 0.f, 0.f, 0.f};

    for (int kk = 0; kk < 512; kk += 64) {
        __syncthreads();
        // ---- stage A hi/lo: 128 rows x 8 chunks(16B), swizzled source ----
#pragma unroll
        for (int p = 0; p < 4; ++p) {
            int s = p * 256 + tid;
            int row = s >> 3, j = s & 7;
            int kc = (j ^ (row & 7)) << 3;
            size_t goff = (size_t)(m0 + row) * 512 + kk + kc;
            unsigned ldsb = (unsigned)(p * 256 + wv * 64) * 16;
            __builtin_amdgcn_global_load_lds((const __attribute__((address_space(1))) void*)(Phi + goff),
                                             (__attribute__((address_space(3))) void*)(smem + ldsb), 16, 0, 0);
            __builtin_amdgcn_global_load_lds((const __attribute__((address_space(1))) void*)(Plo + goff),
                                             (__attribute__((address_space(3))) void*)(smem + 16384 + ldsb), 16, 0, 0);
        }
        // ---- stage B: 128 sites x 8 chunks ----
#pragma unroll
        for (int p = 0; p < 4; ++p) {
            int s = p * 256 + tid;
            int row = s >> 3, j = s & 7;
            int kc = (j ^ (row & 7)) << 3;
            size_t goff = (size_t)(n0 + row) * 512 + kk + kc;
            unsigned ldsb = 32768u + (unsigned)(p * 256 + wv * 64) * 16;
            __builtin_amdgcn_global_load_lds((const __attribute__((address_space(1))) void*)(Bm + goff),
                                             (__attribute__((address_space(3))) void*)(smem + ldsb), 16, 0, 0);
        }
        __syncthreads();

        // ---- compute: 2 K-halves x 4 mi x 4 ni x (hi+lo) ----
#pragma unroll
        for (int ks = 0; ks < 2; ++ks) {
            bf16x8 ah[4], al[4];
#pragma unroll
            for (int mi = 0; mi < 4; ++mi) {
                int row = wr * 64 + mi * 16 + frow;
                int jj = (ks * 4 + g4) ^ (row & 7);
                ah[mi] = *(const bf16x8*)(smem + row * 128 + jj * 16);
                al[mi] = *(const bf16x8*)(smem + 16384 + row * 128 + jj * 16);
            }
#pragma unroll
            for (int ni = 0; ni < 4; ++ni) {
                int site = wc * 64 + ni * 16 + frow;
                int jj = (ks * 4 + g4) ^ (site & 7);
                bf16x8 bb = *(const bf16x8*)(smem + 32768 + site * 128 + jj * 16);
#pragma unroll
                for (int mi = 0; mi < 4; ++mi) {
                    acc[mi][ni] = __builtin_amdgcn_mfma_f32_16x16x32_bf16(ah[mi], bb, acc[mi][ni], 0, 0, 0);
                    acc[mi][ni] = __builtin_amdgcn_mfma_f32_16x16x32_bf16(al[mi], bb, acc[mi][ni], 0, 0, 0);
                }
            }
        }
    }

    // ---- epilogue: BN + bias (folded), direct store ----
#pragma unroll
    for (int mi = 0; mi < 4; ++mi)
#pragma unroll
        for (int ni = 0; ni < 4; ++ni)
#pragma unroll
            for (int r = 0; r < 4; ++r) {
                int gr = m0 + wr * 64 + mi * 16 + g4 * 4 + r;
                int gc = n0 + wc * 64 + ni * 16 + frow;
                float vout = acc[mi][ni][r] * scale[gr] + shift[gr];
                int tb = gc >> 10, nn = gc & 1023;
                out[((size_t)(tb * C_ + gr)) * N_ + nn] = vout;
            }
}

// =====================================================================
// K4: M2T = (K^T V)^T * 0.125, exact hi/lo bf16 split.  One block per (tb,h).
// =====================================================================
__global__ __launch_bounds__(256) void m2t_kernel(const u64* __restrict__ kbit,
                                                  const u64* __restrict__ vbit,
                                                  bf16_t* __restrict__ m2h,
                                                  bf16_t* __restrict__ m2l)
{
    __shared__ u64 Kb[64][17];
    __shared__ u64 Vb[64][17];
    __shared__ float M2f[64][64];
    const int tid = threadIdx.x;
    const int h  = blockIdx.x;
    const int tb = blockIdx.y;

    const u64* kbase = kbit + (size_t)(tb * NH_ + h) * 1024;
    const u64* vbase = vbit + (size_t)(tb * NH_ + h) * 1024;
    for (int i = tid; i < 1024; i += 256) {
        Kb[i >> 4][i & 15] = kbase[i];
        Vb[i >> 4][i & 15] = vbase[i];
    }
    __syncthreads();

    const int d1 = tid >> 2, l2 = tid & 3;
    int cnt[16];
#pragma unroll
    for (int jj = 0; jj < 16; ++jj) cnt[jj] = 0;
    for (int w = 0; w < 16; ++w) {
        u64 kw = Kb[d1][w];
#pragma unroll
        for (int jj = 0; jj < 16; ++jj)
            cnt[jj] += __popcll(kw & Vb[l2 + 4 * jj][w]);
    }
#pragma unroll
    for (int jj = 0; jj < 16; ++jj)
        M2f[d1][l2 + 4 * jj] = (float)cnt[jj] * 0.125f;
    __syncthreads();

    const int d2 = tid >> 2, d1b = (tid & 3) * 16;
    bf16x8 h0, h1, l0, l1;
#pragma unroll
    for (int j = 0; j < 16; ++j) {
        float m = M2f[d1b + j][d2];
        bf16_t hi = (bf16_t)m;
        bf16_t lo = (bf16_t)(m - (float)hi);
        if (j < 8) { h0[j] = hi; l0[j] = lo; } else { h1[j - 8] = hi; l1[j - 8] = lo; }
    }
    size_t base = (size_t)(tb * NH_ + h) * 4096 + tid * 16;
    *(bf16x8*)&m2h[base]     = h0;
    *(bf16x8*)&m2h[base + 8] = h1;
    *(bf16x8*)&m2l[base]     = l0;
    *(bf16x8*)&m2l[base + 8] = l1;
}

// =====================================================================
// K5: O^T = M2T @ Q^T via MFMA (exact), fused attn-LIF, spikes -> osT.
// =====================================================================
__global__ __launch_bounds__(256) void o_kernel(const bf16_t* __restrict__ qsT,
                                                const bf16_t* __restrict__ m2h,
                                                const bf16_t* __restrict__ m2l,
                                                bf16_t* __restrict__ osT)
{
    __shared__ bf16_t Ah[64][72];
    __shared__ bf16_t Al[64][72];
    __shared__ bf16_t Bq[128][72];

    const int tid  = threadIdx.x;
    const int lane = tid & 63;
    const int wv   = tid >> 6;
    const int nt = blockIdx.x, h = blockIdx.y, b = blockIdx.z;
    const int n0 = nt * 128;
    const int frow = lane & 15;
    const int g    = lane >> 4;

    float vst[4][2][4];
#pragma unroll
    for (int mi = 0; mi < 4; ++mi)
#pragma unroll
        for (int ni = 0; ni < 2; ++ni)
#pragma unroll
            for (int r = 0; r < 4; ++r) vst[mi][ni][r] = 0.f;

    for (int t = 0; t < T_; ++t) {
        const int tb = t * B_ + b;
        __syncthreads();
        {
            int row = tid >> 2, col = (tid & 3) * 16;
            size_t gbase = (size_t)(tb * NH_ + h) * 4096 + row * 64 + col;
            *(bf16x8*)&Ah[row][col]     = *(const bf16x8*)&m2h[gbase];
            *(bf16x8*)&Ah[row][col + 8] = *(const bf16x8*)&m2h[gbase + 8];
            *(bf16x8*)&Al[row][col]     = *(const bf16x8*)&m2l[gbase];
            *(bf16x8*)&Al[row][col + 8] = *(const bf16x8*)&m2l[gbase + 8];
        }
#pragma unroll
        for (int w = 0; w < 4; ++w) {
            int id = w * 256 + tid;
            int row = id >> 3, cg = (id & 7) * 8;
            *(bf16x8*)&Bq[row][cg] =
                *(const bf16x8*)&qsT[(size_t)((tb << 10) + n0 + row) * C_ + h * 64 + cg];
        }
        __syncthreads();

        bf16x8 afh[4][2], afl[4][2], bfq[2][2];
#pragma unroll
        for (int mi = 0; mi < 4; ++mi)
#pragma unroll
            for (int ks = 0; ks < 2; ++ks) {
                afh[mi][ks] = *(const bf16x8*)&Ah[mi * 16 + frow][ks * 32 + g * 8];
                afl[mi][ks] = *(const bf16x8*)&Al[mi * 16 + frow][ks * 32 + g * 8];
            }
#pragma unroll
        for (int ni = 0; ni < 2; ++ni)
#pragma unroll
            for (int ks = 0; ks < 2; ++ks)
                bfq[ni][ks] = *(const bf16x8*)&Bq[wv * 32 + ni * 16 + frow][ks * 32 + g * 8];

        f32x4 acc[4][2];
#pragma unroll
        for (int mi = 0; mi < 4; ++mi)
#pragma unroll
            for (int ni = 0; ni < 2; ++ni) acc[mi][ni] = f32x4{0.f, 0.f, 0.f, 0.f};

#pragma unroll
        for (int ks = 0; ks < 2; ++ks)
#pragma unroll
            for (int mi = 0; mi < 4; ++mi)
#pragma unroll
                for (int ni = 0; ni < 2; ++ni) {
                    acc[mi][ni] = __builtin_amdgcn_mfma_f32_16x16x32_bf16(afh[mi][ks], bfq[ni][ks], acc[mi][ni], 0, 0, 0);
                    acc[mi][ni] = __builtin_amdgcn_mfma_f32_16x16x32_bf16(afl[mi][ks], bfq[ni][ks], acc[mi][ni], 0, 0, 0);
                }

#pragma unroll
        for (int mi = 0; mi < 4; ++mi)
#pragma unroll
            for (int ni = 0; ni < 2; ++ni) {
                ushort4 pk;
                unsigned short* pp = &pk.x;
#pragma unroll
                for (int r = 0; r < 4; ++r) {
                    float o = acc[mi][ni][r];
                    float vn = vst[mi][ni][r] + (o - vst[mi][ni][r]) * 0.5f;
                    bool s = (vn >= 0.5f);
                    vst[mi][ni][r] = s ? 0.f : vn;
                    pp[r] = s ? 0x3F80 : 0;
                }
                size_t off = (size_t)((tb << 10) + n0 + wv * 32 + ni * 16 + frow) * C_
                           + h * 64 + mi * 16 + g * 4;
                *(ushort4*)&osT[off] = pk;
            }
    }
}

// =====================================================================
extern "C" void kernel_launch(void* const* d_in, const int* in_sizes, int n_in,
                              void* d_out, int out_size, void* d_ws, size_t ws_size,
                              hipStream_t stream)
{
    const float* x   = (const float*)d_in[0];
    const float* Wq  = (const float*)d_in[1];
    const float* qg  = (const float*)d_in[2];
    const float* qb  = (const float*)d_in[3];
    const float* qm  = (const float*)d_in[4];
    const float* qv  = (const float*)d_in[5];
    const float* Wk  = (const float*)d_in[6];
    const float* kg  = (const float*)d_in[7];
    const float* kb  = (const float*)d_in[8];
    const float* km  = (const float*)d_in[9];
    const float* kv  = (const float*)d_in[10];
    const float* Wv  = (const float*)d_in[11];
    const float* vg  = (const float*)d_in[12];
    const float* vb  = (const float*)d_in[13];
    const float* vm  = (const float*)d_in[14];
    const float* vv  = (const float*)d_in[15];
    const float* Wp  = (const float*)d_in[16];
    const float* bp  = (const float*)d_in[17];
    const float* pg  = (const float*)d_in[18];
    const float* pb  = (const float*)d_in[19];
    const float* pm  = (const float*)d_in[20];
    const float* pv  = (const float*)d_in[21];

    char* ws = (char*)d_ws;
    bf16_t* xsT    = (bf16_t*)(ws + XS_OFF);
    bf16_t* Ahi    = (bf16_t*)(ws + AHI_OFF);
    bf16_t* Alo    = (bf16_t*)(ws + ALO_OFF);
    bf16_t* Phi    = (bf16_t*)(ws + PHI_OFF);
    bf16_t* Plo    = (bf16_t*)(ws + PLO_OFF);
    float*  scv    = (float*)(ws + SC_OFF);
    float*  shv    = (float*)(ws + SH_OFF);
    float*  psc    = (float*)(ws + PSC_OFF);
    float*  psh    = (float*)(ws + PSH_OFF);
    bf16_t* qsT    = (bf16_t*)(ws + QS_OFF);
    u32*    kbits32= (u32*)(ws + KB_OFF);
    u32*    vbits32= (u32*)(ws + VB_OFF);
    u64*    kbits  = (u64*)(ws + KB_OFF);
    u64*    vbits  = (u64*)(ws + VB_OFF);
    bf16_t* m2h    = (bf16_t*)(ws + M2H_OFF);
    bf16_t* m2l    = (bf16_t*)(ws + M2L_OFF);
    bf16_t* osT    = (bf16_t*)(ws + XS_OFF);   // ALIAS: xsT dead after gemm_qkv_lif
    float*  out    = (float*)d_out;

    prep_kernel<<<dim3(3072), dim3(256), 0, stream>>>(
        Wq, Wk, Wv, Wp, qg, qb, qm, qv, kg, kb, km, kv, vg, vb, vm, vv,
        bp, pg, pb, pm, pv, Ahi, Alo, Phi, Plo, scv, shv, psc, psh);

    lif_x_kernel<<<dim3(16, 8, 4), dim3(256), 0, stream>>>(x, xsT);

    gemm_qkv_lif<<<dim3(128, 12), dim3(256), 0, stream>>>(
        Ahi, Alo, xsT, scv, shv, qsT, kbits32, vbits32);

    m2t_kernel<<<dim3(8, 16), dim3(256), 0, stream>>>(kbits, vbits, m2h, m2l);

    o_kernel<<<dim3(8, 8, 4), dim3(256), 0, stream>>>(qsT, m2h, m2l, osT);

    gemm_proj<<<dim3(128, 4), dim3(256), 0, stream>>>(Phi, Plo, osT, psc, psh, out);

    (void)in_sizes; (void)n_in; (void)out_size; (void)ws_size;
}

// Round 10
// 213.752 us; speedup vs baseline: 1.0822x; 1.0134x over previous
//
#include <hip/hip_runtime.h>
#include <hip/hip_bf16.h>
#include <stdint.h>

// ---------------- problem constants ----------------
#define T_  4
#define B_  4
#define C_  512
#define N_  1024       // H*W
#define NH_ 8
#define HD_ 64
#define NP_ 16384      // T*B*N
#define EPS_ 1e-5f

typedef __bf16 bf16_t;
typedef __bf16 bf16x8 __attribute__((ext_vector_type(8)));
typedef float  f32x4  __attribute__((ext_vector_type(4)));
typedef unsigned short u16x4 __attribute__((ext_vector_type(4)));
typedef unsigned char  u8x4  __attribute__((ext_vector_type(4)));
typedef unsigned long long u64;
typedef unsigned int u32;

// ---------------- workspace layout (bytes) ----------------
#define XS_OFF   0ULL                      // bf16 XsT[16384][512] ; later osT
#define AHI_OFF  16777216ULL               // bf16 [1536][512]  stacked Wq/Wk/Wv hi
#define ALO_OFF  18350080ULL               // bf16 [1536][512]  lo
#define PHI_OFF  19922944ULL               // bf16 [512][512]   Wp hi
#define PLO_OFF  20447232ULL               // bf16 [512][512]   Wp lo
#define SC_OFF   20971520ULL               // f32 [1536] BN scale (stacked q,k,v)
#define SH_OFF   20977664ULL               // f32 [1536] BN shift
#define PSC_OFF  20983808ULL               // f32 [512]
#define PSH_OFF  20985856ULL               // f32 [512]  (includes bp folded)
#define QS_OFF   20987904ULL               // bf16 qsT[16384][512]  q spikes (transposed)
#define KB_OFF   37765120ULL               // u64 [16][8][64][16] k spike bits
#define VB_OFF   38813696ULL               // u64 [16][8][64][16]
#define M2H_OFF  39862272ULL               // bf16 M2T_hi[128][64][64]
#define M2L_OFF  40910848ULL               // bf16 M2T_lo[128][64][64]

// =====================================================================
// K0: MERGED prep (weight split + BN fold, blockIdx.z==4) and
//     lif_x (proj_lif on x -> XsT[n'][c], blockIdx.z<4 -> b).
// =====================================================================
__global__ __launch_bounds__(256) void prep_lif_kernel(
    const float* __restrict__ x, bf16_t* __restrict__ xsT,
    const float* __restrict__ Wq, const float* __restrict__ Wk,
    const float* __restrict__ Wv, const float* __restrict__ Wp,
    const float* __restrict__ qg, const float* __restrict__ qb, const float* __restrict__ qm, const float* __restrict__ qv,
    const float* __restrict__ kg, const float* __restrict__ kb, const float* __restrict__ km, const float* __restrict__ kv,
    const float* __restrict__ vg, const float* __restrict__ vb, const float* __restrict__ vm, const float* __restrict__ vv,
    const float* __restrict__ bp,
    const float* __restrict__ pg, const float* __restrict__ pb, const float* __restrict__ pm, const float* __restrict__ pv,
    bf16_t* __restrict__ Ahi, bf16_t* __restrict__ Alo,
    bf16_t* __restrict__ Phi, bf16_t* __restrict__ Plo,
    float* __restrict__ scale, float* __restrict__ shift,
    float* __restrict__ pscale, float* __restrict__ pshift)
{
    __shared__ bf16_t St[64 * 72];
    const int tid = threadIdx.x;

    if (blockIdx.z == 4) {
        // ---------------- prep branch: 128 virtual blocks ----------------
        const int i0 = (blockIdx.y * 16 + blockIdx.x) * 256 + tid;
        const int stride = 128 * 256;
        for (int idx = i0; idx < 1536 * 512; idx += stride) {
            int r = idx >> 9;
            int br = r >> 9;
            const float* W = (br == 0) ? Wq : (br == 1) ? Wk : Wv;
            float w = W[((r & 511) << 9) + (idx & 511)];
            bf16_t h = (bf16_t)w;
            Ahi[idx] = h;
            Alo[idx] = (bf16_t)(w - (float)h);
        }
        for (int idx = i0; idx < 512 * 512; idx += stride) {
            float w = Wp[idx];
            bf16_t h = (bf16_t)w;
            Phi[idx] = h;
            Plo[idx] = (bf16_t)(w - (float)h);
        }
        for (int idx = i0; idx < 1536; idx += stride) {
            int br = idx >> 9, d = idx & 511;
            const float* g  = (br == 0) ? qg : (br == 1) ? kg : vg;
            const float* bb = (br == 0) ? qb : (br == 1) ? kb : vb;
            const float* mm = (br == 0) ? qm : (br == 1) ? km : vm;
            const float* vr = (br == 0) ? qv : (br == 1) ? kv : vv;
            float sc = g[d] / sqrtf(vr[d] + EPS_);
            scale[idx] = sc;
            shift[idx] = bb[d] - mm[d] * sc;
        }
        for (int idx = i0; idx < 512; idx += stride) {
            float sc = pg[idx] / sqrtf(pv[idx] + EPS_);
            pscale[idx] = sc;
            pshift[idx] = (bp[idx] - pm[idx]) * sc + pb[idx];
        }
        return;
    }

    // ---------------- lif_x branch ----------------
    const int nl  = tid & 63;
    const int c4  = tid >> 6;
    const int n0 = blockIdx.x * 64;
    const int c0 = blockIdx.y * 64;
    const int b  = blockIdx.z;
    float v[16];
#pragma unroll
    for (int k = 0; k < 16; ++k) v[k] = 0.f;

    for (int t = 0; t < T_; ++t) {
        bf16x8 s0, s1;
#pragma unroll
        for (int k = 0; k < 16; ++k) {
            float xv = x[(size_t)((t * B_ + b) * C_ + (c0 + c4 * 16 + k)) * N_ + n0 + nl];
            float vn = v[k] + (xv - v[k]) * 0.5f;
            bool s = (vn >= 1.0f);
            v[k] = s ? 0.0f : vn;
            bf16_t sp = s ? (bf16_t)1.0f : (bf16_t)0.0f;
            if (k < 8) s0[k] = sp; else s1[k - 8] = sp;
        }
        __syncthreads();
        *(bf16x8*)&St[nl * 72 + c4 * 16]     = s0;
        *(bf16x8*)&St[nl * 72 + c4 * 16 + 8] = s1;
        __syncthreads();
#pragma unroll
        for (int it = 0; it < 2; ++it) {
            int id = it * 256 + tid;
            int row = id >> 3, sg = id & 7;
            *(bf16x8*)&xsT[((size_t)((t * B_ + b) << 10) + n0 + row) * C_ + c0 + sg * 8] =
                *(const bf16x8*)&St[row * 72 + sg * 8];
        }
    }
}

// =====================================================================
// K2: FUSED qkv GEMM + BN + LIF + spike emit  (t-inner accumulators).
//  PROVEN VERSION (61.6 us): BM=128, BN=32 sites, BK=64,
//  single-buffer, 8 barrier-steps, 64 MFMA/step, XOR j^(row&7) swizzle.
//  UNCHANGED (control).
// =====================================================================
__global__ __launch_bounds__(256) void gemm_qkv_lif(
    const bf16_t* __restrict__ Ahi, const bf16_t* __restrict__ Alo,
    const bf16_t* __restrict__ xsT,
    const float* __restrict__ scale, const float* __restrict__ shift,
    bf16_t* __restrict__ qsT, u32* __restrict__ kbits, u32* __restrict__ vbits)
{
    __shared__ __align__(16) unsigned char smem[49152];  // AH 16K | AL 16K | B 16K

    const int tid  = threadIdx.x;
    const int lane = tid & 63;
    const int wv   = tid >> 6;
    const int wr   = wv >> 1, wc = wv & 1;     // wave tile 64(c) x 16(sites)
    const int m0   = blockIdx.y * 128;         // stacked channel base
    const int branch = m0 >> 9;                // 0=q 1=k 2=v
    const int site0 = blockIdx.x * 32;
    const int b    = site0 >> 10;
    const int n0   = site0 & 1023;

    const int frow = lane & 15;
    const int g4   = lane >> 4;

    f32x4 acc[4][4];                           // [t][mi]
#pragma unroll
    for (int t = 0; t < 4; ++t)
#pragma unroll
        for (int mi = 0; mi < 4; ++mi) acc[t][mi] = f32x4{0.f, 0.f, 0.f, 0.f};

    for (int kk = 0; kk < 512; kk += 64) {
        __syncthreads();                       // prev step's readers done
        // ---- stage A hi/lo: 128 rows x 8 chunks(16B), swizzled source ----
#pragma unroll
        for (int p = 0; p < 4; ++p) {
            int s = p * 256 + tid;
            int row = s >> 3, j = s & 7;
            int kc = (j ^ (row & 7)) << 3;     // pre-swizzled source chunk
            size_t goff = (size_t)(m0 + row) * 512 + kk + kc;
            unsigned ldsb = (unsigned)(p * 256 + wv * 64) * 16;
            __builtin_amdgcn_global_load_lds((const __attribute__((address_space(1))) void*)(Ahi + goff),
                                             (__attribute__((address_space(3))) void*)(smem + ldsb), 16, 0, 0);
            __builtin_amdgcn_global_load_lds((const __attribute__((address_space(1))) void*)(Alo + goff),
                                             (__attribute__((address_space(3))) void*)(smem + 16384 + ldsb), 16, 0, 0);
        }
        // ---- stage B: 4t x 32 rows x 8 chunks ----
#pragma unroll
        for (int p = 0; p < 4; ++p) {
            int s = p * 256 + tid;
            int t = s >> 8, row = (s >> 3) & 31, j = s & 7;
            int kc = (j ^ (row & 7)) << 3;
            size_t goff = ((size_t)((t * B_ + b) << 10) + n0 + row) * 512 + kk + kc;
            unsigned ldsb = 32768u + (unsigned)(p * 256 + wv * 64) * 16;
            __builtin_amdgcn_global_load_lds((const __attribute__((address_space(1))) void*)(xsT + goff),
                                             (__attribute__((address_space(3))) void*)(smem + ldsb), 16, 0, 0);
        }
        __syncthreads();

        // ---- compute: 2 K-halves x 4 t x 4 mi x (hi+lo) ----
#pragma unroll
        for (int ks = 0; ks < 2; ++ks) {
            bf16x8 ah[4], al[4];
#pragma unroll
            for (int mi = 0; mi < 4; ++mi) {
                int row = wr * 64 + mi * 16 + frow;
                int jj = (ks * 4 + g4) ^ (row & 7);
                ah[mi] = *(const bf16x8*)(smem + row * 128 + jj * 16);
                al[mi] = *(const bf16x8*)(smem + 16384 + row * 128 + jj * 16);
            }
#pragma unroll
            for (int t = 0; t < 4; ++t) {
                int rowb = wc * 16 + frow;
                int jj = (ks * 4 + g4) ^ (rowb & 7);
                bf16x8 bb = *(const bf16x8*)(smem + 32768 + t * 4096 + rowb * 128 + jj * 16);
#pragma unroll
                for (int mi = 0; mi < 4; ++mi) {
                    acc[t][mi] = __builtin_amdgcn_mfma_f32_16x16x32_bf16(ah[mi], bb, acc[t][mi], 0, 0, 0);
                    acc[t][mi] = __builtin_amdgcn_mfma_f32_16x16x32_bf16(al[mi], bb, acc[t][mi], 0, 0, 0);
                }
            }
        }
    }

    // ---------------- epilogue: BN + LIF chain + emit ----------------
    if (branch == 0) {
        bf16_t* Tt = (bf16_t*)smem;            // [32 sites][136] stride
        u16x4 qpk[4][4];                       // [t][mi]
#pragma unroll
        for (int mi = 0; mi < 4; ++mi)
#pragma unroll
            for (int r = 0; r < 4; ++r) {
                int gr = m0 + wr * 64 + mi * 16 + g4 * 4 + r;
                float sc = scale[gr], sh = shift[gr];
                float vv = 0.f;
#pragma unroll
                for (int t = 0; t < 4; ++t) {
                    float y = acc[t][mi][r] * sc + sh;
                    float vn = vv + (y - vv) * 0.5f;
                    bool s = (vn >= 1.0f);
                    vv = s ? 0.f : vn;
                    qpk[t][mi][r] = s ? 0x3F80 : 0;
                }
            }
#pragma unroll
        for (int t = 0; t < 4; ++t) {
            const int tb = t * B_ + b;
            __syncthreads();
#pragma unroll
            for (int mi = 0; mi < 4; ++mi) {
                int nl = wc * 16 + frow;
                int cl = wr * 64 + mi * 16 + g4 * 4;
                *(u16x4*)&Tt[nl * 136 + cl] = qpk[t][mi];
            }
            __syncthreads();
#pragma unroll
            for (int it = 0; it < 2; ++it) {
                int id = it * 256 + tid;
                int row = id >> 4, sg = id & 15;
                *(bf16x8*)&qsT[((size_t)(tb << 10) + n0 + row) * 512 + m0 + sg * 8] =
                    *(const bf16x8*)&Tt[row * 136 + sg * 8];
            }
        }
    } else {
        unsigned char* Sb = (unsigned char*)smem;   // [32 sites][132] stride
        u32* bdst = (branch == 1) ? kbits : vbits;
        u8x4 kpk[4][4];
#pragma unroll
        for (int mi = 0; mi < 4; ++mi)
#pragma unroll
            for (int r = 0; r < 4; ++r) {
                int gr = m0 + wr * 64 + mi * 16 + g4 * 4 + r;
                float sc = scale[gr], sh = shift[gr];
                float vv = 0.f;
#pragma unroll
                for (int t = 0; t < 4; ++t) {
                    float y = acc[t][mi][r] * sc + sh;
                    float vn = vv + (y - vv) * 0.5f;
                    bool s = (vn >= 1.0f);
                    vv = s ? 0.f : vn;
                    kpk[t][mi][r] = s ? 1 : 0;
                }
            }
#pragma unroll
        for (int t = 0; t < 4; ++t) {
            const int tb = t * B_ + b;
            __syncthreads();
#pragma unroll
            for (int mi = 0; mi < 4; ++mi) {
                int nl = wc * 16 + frow;
                int cl = wr * 64 + mi * 16 + g4 * 4;
                *(u8x4*)&Sb[nl * 132 + cl] = kpk[t][mi];
            }
            __syncthreads();
#pragma unroll
            for (int i = 0; i < 16; ++i) {
                int item = wv * 16 + i;
                int c = item * 2 + (lane >> 5);
                unsigned char vb_ = Sb[(lane & 31) * 132 + c];
                u64 mask = __ballot(vb_ != 0);
                if (lane == 0) {
                    int r0 = (m0 & 511) + item * 2;
                    int r1 = r0 + 1;
                    bdst[((size_t)(tb * NH_ + (r0 >> 6)) * 64 + (r0 & 63)) * 32 + (n0 >> 5)] = (u32)mask;
                    bdst[((size_t)(tb * NH_ + (r1 >> 6)) * 64 + (r1 & 63)) * 32 + (n0 >> 5)] = (u32)(mask >> 32);
                }
            }
        }
    }
}

// =====================================================================
// K6: proj GEMM — geometry clone of the proven qkv structure.
//  UNCHANGED (control).
// =====================================================================
__global__ __launch_bounds__(256) void gemm_proj(
    const bf16_t* __restrict__ Phi, const bf16_t* __restrict__ Plo,
    const bf16_t* __restrict__ Bm,
    const float* __restrict__ scale, const float* __restrict__ shift,
    float* __restrict__ out)
{
    __shared__ __align__(16) unsigned char smem[49152];  // AH 16K | AL 16K | B 16K

    const int tid  = threadIdx.x;
    const int lane = tid & 63;
    const int wv   = tid >> 6;
    const int wr   = wv >> 1, wc = wv & 1;     // wave tile 64(c) x 64(sites)
    const int m0   = blockIdx.y * 128;
    const int n0   = blockIdx.x * 128;         // global site column base

    const int frow = lane & 15;
    const int g4   = lane >> 4;

    f32x4 acc[4][4];                           // [mi][ni]
#pragma unroll
    for (int i = 0; i < 4; ++i)
#pragma unroll
        for (int j = 0; j < 4; ++j) acc[i][j] = f32x4{0.f, 0.f, 0.f, 0.f};

    for (int kk = 0; kk < 512; kk += 64) {
        __syncthreads();
        // ---- stage A hi/lo: 128 rows x 8 chunks(16B), swizzled source ----
#pragma unroll
        for (int p = 0; p < 4; ++p) {
            int s = p * 256 + tid;
            int row = s >> 3, j = s & 7;
            int kc = (j ^ (row & 7)) << 3;
            size_t goff = (size_t)(m0 + row) * 512 + kk + kc;
            unsigned ldsb = (unsigned)(p * 256 + wv * 64) * 16;
            __builtin_amdgcn_global_load_lds((const __attribute__((address_space(1))) void*)(Phi + goff),
                                             (__attribute__((address_space(3))) void*)(smem + ldsb), 16, 0, 0);
            __builtin_amdgcn_global_load_lds((const __attribute__((address_space(1))) void*)(Plo + goff),
                                             (__attribute__((address_space(3))) void*)(smem + 16384 + ldsb), 16, 0, 0);
        }
        // ---- stage B: 128 sites x 8 chunks ----
#pragma unroll
        for (int p = 0; p < 4; ++p) {
            int s = p * 256 + tid;
            int row = s >> 3, j = s & 7;
            int kc = (j ^ (row & 7)) << 3;
            size_t goff = (size_t)(n0 + row) * 512 + kk + kc;
            unsigned ldsb = 32768u + (unsigned)(p * 256 + wv * 64) * 16;
            __builtin_amdgcn_global_load_lds((const __attribute__((address_space(1))) void*)(Bm + goff),
                                             (__attribute__((address_space(3))) void*)(smem + ldsb), 16, 0, 0);
        }
        __syncthreads();

        // ---- compute: 2 K-halves x 4 mi x 4 ni x (hi+lo) ----
#pragma unroll
        for (int ks = 0; ks < 2; ++ks) {
            bf16x8 ah[4], al[4];
#pragma unroll
            for (int mi = 0; mi < 4; ++mi) {
                int row = wr * 64 + mi * 16 + frow;
                int jj = (ks * 4 + g4) ^ (row & 7);
                ah[mi] = *(const bf16x8*)(smem + row * 128 + jj * 16);
                al[mi] = *(const bf16x8*)(smem + 16384 + row * 128 + jj * 16);
            }
#pragma unroll
            for (int ni = 0; ni < 4; ++ni) {
                int site = wc * 64 + ni * 16 + frow;
                int jj = (ks * 4 + g4) ^ (site & 7);
                bf16x8 bb = *(const bf16x8*)(smem + 32768 + site * 128 + jj * 16);
#pragma unroll
                for (int mi = 0; mi < 4; ++mi) {
                    acc[mi][ni] = __builtin_amdgcn_mfma_f32_16x16x32_bf16(ah[mi], bb, acc[mi][ni], 0, 0, 0);
                    acc[mi][ni] = __builtin_amdgcn_mfma_f32_16x16x32_bf16(al[mi], bb, acc[mi][ni], 0, 0, 0);
                }
            }
        }
    }

    // ---- epilogue: BN + bias (folded), direct store ----
#pragma unroll
    for (int mi = 0; mi < 4; ++mi)
#pragma unroll
        for (int ni = 0; ni < 4; ++ni)
#pragma unroll
            for (int r = 0; r < 4; ++r) {
                int gr = m0 + wr * 64 + mi * 16 + g4 * 4 + r;
                int gc = n0 + wc * 64 + ni * 16 + frow;
                float vout = acc[mi][ni][r] * scale[gr] + shift[gr];
                int tb = gc >> 10, nn = gc & 1023;
                out[((size_t)(tb * C_ + gr)) * N_ + nn] = vout;
            }
}

// =====================================================================
// K4: M2T = (K^T V)^T * 0.125, exact hi/lo bf16 split.  One block per (tb,h).
//  UNCHANGED.
// =====================================================================
__global__ __launch_bounds__(256) void m2t_kernel(const u64* __restrict__ kbit,
                                                  const u64* __restrict__ vbit,
                                                  bf16_t* __restrict__ m2h,
                                                  bf16_t* __restrict__ m2l)
{
    __shared__ u64 Kb[64][17];
    __shared__ u64 Vb[64][17];
    __shared__ float M2f[64][64];
    const int tid = threadIdx.x;
    const int h  = blockIdx.x;
    const int tb = blockIdx.y;

    const u64* kbase = kbit + (size_t)(tb * NH_ + h) * 1024;
    const u64* vbase = vbit + (size_t)(tb * NH_ + h) * 1024;
    for (int i = tid; i < 1024; i += 256) {
        Kb[i >> 4][i & 15] = kbase[i];
        Vb[i >> 4][i & 15] = vbase[i];
    }
    __syncthreads();

    const int d1 = tid >> 2, l2 = tid & 3;
    int cnt[16];
#pragma unroll
    for (int jj = 0; jj < 16; ++jj) cnt[jj] = 0;
    for (int w = 0; w < 16; ++w) {
        u64 kw = Kb[d1][w];
#pragma unroll
        for (int jj = 0; jj < 16; ++jj)
            cnt[jj] += __popcll(kw & Vb[l2 + 4 * jj][w]);
    }
#pragma unroll
    for (int jj = 0; jj < 16; ++jj)
        M2f[d1][l2 + 4 * jj] = (float)cnt[jj] * 0.125f;
    __syncthreads();

    const int d2 = tid >> 2, d1b = (tid & 3) * 16;
    bf16x8 h0, h1, l0, l1;
#pragma unroll
    for (int j = 0; j < 16; ++j) {
        float m = M2f[d1b + j][d2];
        bf16_t hi = (bf16_t)m;
        bf16_t lo = (bf16_t)(m - (float)hi);
        if (j < 8) { h0[j] = hi; l0[j] = lo; } else { h1[j - 8] = hi; l1[j - 8] = lo; }
    }
    size_t base = (size_t)(tb * NH_ + h) * 4096 + tid * 16;
    *(bf16x8*)&m2h[base]     = h0;
    *(bf16x8*)&m2h[base + 8] = h1;
    *(bf16x8*)&m2l[base]     = l0;
    *(bf16x8*)&m2l[base + 8] = l1;
}

// =====================================================================
// K5 v2: O^T = M2T @ Q^T via MFMA (exact), fused attn-LIF, spikes -> osT.
//  64-site blocks (512 total, 2-4/CU) for latency hiding; output through
//  LDS transpose tile -> coalesced 16B osT stores.
// =====================================================================
__global__ __launch_bounds__(256) void o_kernel(const bf16_t* __restrict__ qsT,
                                                const bf16_t* __restrict__ m2h,
                                                const bf16_t* __restrict__ m2l,
                                                bf16_t* __restrict__ osT)
{
    __shared__ bf16_t Ah[64][72];
    __shared__ bf16_t Al[64][72];
    __shared__ bf16_t Bq[64][72];
    __shared__ bf16_t Ot[64][72];       // [site_l][d]

    const int tid  = threadIdx.x;
    const int lane = tid & 63;
    const int wv   = tid >> 6;
    const int nt = blockIdx.x, h = blockIdx.y, b = blockIdx.z;
    const int n0 = nt * 64;
    const int frow = lane & 15;
    const int g    = lane >> 4;

    float vst[4][4];                    // [mi][r]
#pragma unroll
    for (int mi = 0; mi < 4; ++mi)
#pragma unroll
        for (int r = 0; r < 4; ++r) vst[mi][r] = 0.f;

    for (int t = 0; t < T_; ++t) {
        const int tb = t * B_ + b;
        __syncthreads();                // prev t: frag reads + Ot copy-out done
        {   // stage M2 hi/lo (64x64)
            int row = tid >> 2, col = (tid & 3) * 16;
            size_t gbase = (size_t)(tb * NH_ + h) * 4096 + row * 64 + col;
            *(bf16x8*)&Ah[row][col]     = *(const bf16x8*)&m2h[gbase];
            *(bf16x8*)&Ah[row][col + 8] = *(const bf16x8*)&m2h[gbase + 8];
            *(bf16x8*)&Al[row][col]     = *(const bf16x8*)&m2l[gbase];
            *(bf16x8*)&Al[row][col + 8] = *(const bf16x8*)&m2l[gbase + 8];
        }
#pragma unroll
        for (int it = 0; it < 2; ++it) {   // stage Q tile (64 sites x 64 c)
            int id = it * 256 + tid;
            int row = id >> 3, cg = (id & 7) * 8;
            *(bf16x8*)&Bq[row][cg] =
                *(const bf16x8*)&qsT[(size_t)((tb << 10) + n0 + row) * C_ + h * 64 + cg];
        }
        __syncthreads();

        bf16x8 afh[4][2], afl[4][2], bfq[2];
#pragma unroll
        for (int mi = 0; mi < 4; ++mi)
#pragma unroll
            for (int ks = 0; ks < 2; ++ks) {
                afh[mi][ks] = *(const bf16x8*)&Ah[mi * 16 + frow][ks * 32 + g * 8];
                afl[mi][ks] = *(const bf16x8*)&Al[mi * 16 + frow][ks * 32 + g * 8];
            }
#pragma unroll
        for (int ks = 0; ks < 2; ++ks)
            bfq[ks] = *(const bf16x8*)&Bq[wv * 16 + frow][ks * 32 + g * 8];

        f32x4 acc[4];
#pragma unroll
        for (int mi = 0; mi < 4; ++mi) acc[mi] = f32x4{0.f, 0.f, 0.f, 0.f};

#pragma unroll
        for (int ks = 0; ks < 2; ++ks)
#pragma unroll
            for (int mi = 0; mi < 4; ++mi) {
                acc[mi] = __builtin_amdgcn_mfma_f32_16x16x32_bf16(afh[mi][ks], bfq[ks], acc[mi], 0, 0, 0);
                acc[mi] = __builtin_amdgcn_mfma_f32_16x16x32_bf16(afl[mi][ks], bfq[ks], acc[mi], 0, 0, 0);
            }

        // LIF (v_th=0.5) -> Ot[site_l][d]
#pragma unroll
        for (int mi = 0; mi < 4; ++mi) {
            u16x4 pk;
#pragma unroll
            for (int r = 0; r < 4; ++r) {
                float o = acc[mi][r];
                float vn = vst[mi][r] + (o - vst[mi][r]) * 0.5f;
                bool s = (vn >= 0.5f);
                vst[mi][r] = s ? 0.f : vn;
                pk[r] = s ? 0x3F80 : 0;
            }
            *(u16x4*)&Ot[wv * 16 + frow][mi * 16 + g * 4] = pk;
        }
        __syncthreads();                // Ot complete

        // coalesced copy-out: 64 sites x 64 c (h's channel block)
#pragma unroll
        for (int it = 0; it < 2; ++it) {
            int id = it * 256 + tid;
            int row = id >> 3, sg = (id & 7) * 8;
            *(bf16x8*)&osT[(size_t)((tb << 10) + n0 + row) * C_ + h * 64 + sg] =
                *(const bf16x8*)&Ot[row][sg];
        }
    }
}

// =====================================================================
extern "C" void kernel_launch(void* const* d_in, const int* in_sizes, int n_in,
                              void* d_out, int out_size, void* d_ws, size_t ws_size,
                              hipStream_t stream)
{
    const float* x   = (const float*)d_in[0];
    const float* Wq  = (const float*)d_in[1];
    const float* qg  = (const float*)d_in[2];
    const float* qb  = (const float*)d_in[3];
    const float* qm  = (const float*)d_in[4];
    const float* qv  = (const float*)d_in[5];
    const float* Wk  = (const float*)d_in[6];
    const float* kg  = (const float*)d_in[7];
    const float* kb  = (const float*)d_in[8];
    const float* km  = (const float*)d_in[9];
    const float* kv  = (const float*)d_in[10];
    const float* Wv  = (const float*)d_in[11];
    const float* vg  = (const float*)d_in[12];
    const float* vb  = (const float*)d_in[13];
    const float* vm  = (const float*)d_in[14];
    const float* vv  = (const float*)d_in[15];
    const float* Wp  = (const float*)d_in[16];
    const float* bp  = (const float*)d_in[17];
    const float* pg  = (const float*)d_in[18];
    const float* pb  = (const float*)d_in[19];
    const float* pm  = (const float*)d_in[20];
    const float* pv  = (const float*)d_in[21];

    char* ws = (char*)d_ws;
    bf16_t* xsT    = (bf16_t*)(ws + XS_OFF);
    bf16_t* Ahi    = (bf16_t*)(ws + AHI_OFF);
    bf16_t* Alo    = (bf16_t*)(ws + ALO_OFF);
    bf16_t* Phi    = (bf16_t*)(ws + PHI_OFF);
    bf16_t* Plo    = (bf16_t*)(ws + PLO_OFF);
    float*  scv    = (float*)(ws + SC_OFF);
    float*  shv    = (float*)(ws + SH_OFF);
    float*  psc    = (float*)(ws + PSC_OFF);
    float*  psh    = (float*)(ws + PSH_OFF);
    bf16_t* qsT    = (bf16_t*)(ws + QS_OFF);
    u32*    kbits32= (u32*)(ws + KB_OFF);
    u32*    vbits32= (u32*)(ws + VB_OFF);
    u64*    kbits  = (u64*)(ws + KB_OFF);
    u64*    vbits  = (u64*)(ws + VB_OFF);
    bf16_t* m2h    = (bf16_t*)(ws + M2H_OFF);
    bf16_t* m2l    = (bf16_t*)(ws + M2L_OFF);
    bf16_t* osT    = (bf16_t*)(ws + XS_OFF);   // ALIAS: xsT dead after gemm_qkv_lif
    float*  out    = (float*)d_out;

    // prep + lif_x merged (z<4: lif_x b=z ; z==4: prep)
    prep_lif_kernel<<<dim3(16, 8, 5), dim3(256), 0, stream>>>(
        x, xsT, Wq, Wk, Wv, Wp, qg, qb, qm, qv, kg, kb, km, kv, vg, vb, vm, vv,
        bp, pg, pb, pm, pv, Ahi, Alo, Phi, Plo, scv, shv, psc, psh);

    gemm_qkv_lif<<<dim3(128, 12), dim3(256), 0, stream>>>(
        Ahi, Alo, xsT, scv, shv, qsT, kbits32, vbits32);

    m2t_kernel<<<dim3(8, 16), dim3(256), 0, stream>>>(kbits, vbits, m2h, m2l);

    o_kernel<<<dim3(16, 8, 4), dim3(256), 0, stream>>>(qsT, m2h, m2l, osT);

    gemm_proj<<<dim3(128, 4), dim3(256), 0, stream>>>(Phi, Plo, osT, psc, psh, out);

    (void)in_sizes; (void)n_in; (void)out_size; (void)ws_size;
}